// Round 3
// baseline (710.733 us; speedup 1.0000x reference)
//
#include <hip/hip_runtime.h>

typedef __bf16 bf16x8 __attribute__((ext_vector_type(8)));
typedef float f32x4 __attribute__((ext_vector_type(4)));
typedef unsigned short u16x8 __attribute__((ext_vector_type(8)));
typedef unsigned short u16x4 __attribute__((ext_vector_type(4)));

#define MBY (1ull << 20)

__device__ __forceinline__ unsigned short f2bf(float f) {
  union { float f; unsigned u; } v; v.f = f;
  unsigned r = v.u + 0x7fffu + ((v.u >> 16) & 1u);  // RNE
  return (unsigned short)(r >> 16);
}
__device__ __forceinline__ float bf2f(unsigned short s) {
  union { unsigned u; float f; } v; v.u = ((unsigned)s) << 16;
  return v.f;
}
__device__ __forceinline__ float fexp(float x) {        // native v_exp_f32
  return __builtin_amdgcn_exp2f(x * 1.44269504088896340736f);
}
__device__ __forceinline__ float frcp(float x) {        // native v_rcp_f32 (~1 ulp)
  return __builtin_amdgcn_rcpf(x);
}
// async global->LDS, 16B per lane; lds dest = wave-uniform base + lane*16
__device__ __forceinline__ void gl2lds16(const void* g, void* l) {
  __builtin_amdgcn_global_load_lds(
      (const __attribute__((address_space(1))) unsigned int*)g,
      (__attribute__((address_space(3))) unsigned int*)l, 16, 0, 0);
}

// ---------------- prep: x -> bf16
__global__ void prep_x_kernel(const float* __restrict__ x, unsigned short* __restrict__ xbf) {
  int g = blockIdx.x * 256 + threadIdx.x;
  float4 v = ((const float4*)x)[g];
  u16x4 o;
  o[0] = f2bf(v.x); o[1] = f2bf(v.y); o[2] = f2bf(v.z); o[3] = f2bf(v.w);
  *(u16x4*)(xbf + (size_t)g * 4) = o;
}

// ---------------- prep: weight transposes + gate hi/lo split + softplus table
__global__ void prep_misc_kernel(const float* __restrict__ wx, const float* __restrict__ wy,
                                 const float* __restrict__ wo,
                                 const float* __restrict__ wi, const float* __restrict__ wa,
                                 const float* __restrict__ a_param,
                                 unsigned short* __restrict__ wxT, unsigned short* __restrict__ wyT,
                                 unsigned short* __restrict__ woT,
                                 unsigned short* __restrict__ wiTH, unsigned short* __restrict__ wiTL,
                                 unsigned short* __restrict__ waTH, unsigned short* __restrict__ waTL,
                                 float* __restrict__ spbuf) {
  int bid = blockIdx.x, tid = threadIdx.x;
  if (bid < 3072) {                       // 3 big weights: transpose+bf16
    int mat = bid >> 10;
    int g = (bid & 1023) * 256 + tid;
    int n = g & 511, k = g >> 9;
    const float* src = (mat == 0) ? wx : (mat == 1) ? wy : wo;
    unsigned short* dst = (mat == 0) ? wxT : (mat == 1) ? wyT : woT;
    dst[(size_t)n * 512 + k] = f2bf(src[(size_t)k * 512 + n]);
  } else if (bid < 3200) {                // gate weights: transposed hi/lo split
    int g = (bid - 3072) * 256 + tid;
    int j = g & 63, i = (g >> 6) & 63, h = g >> 12;
    size_t src = (size_t)h * 4096 + (size_t)i * 64 + j;
    size_t dst = (size_t)h * 4096 + (size_t)j * 64 + i;
    float v = wi[src];
    unsigned short hh = f2bf(v);
    wiTH[dst] = hh; wiTL[dst] = f2bf(v - bf2f(hh));
    v = wa[src];
    hh = f2bf(v);
    waTH[dst] = hh; waTL[dst] = f2bf(v - bf2f(hh));
  } else {                                // softplus(a_param) table (accurate, once)
    int g = (bid - 3200) * 256 + tid;
    if (g < 512) {
      float ap = a_param[g];
      spbuf[g] = (ap > 0.f) ? ap + log1pf(expf(-ap)) : log1pf(expf(ap));
    }
  }
}

// ---------------- GEMM1 (dual): xb_pre = x@w_x + b_x ; yb = gelu(x@w_y + b_y)
__global__ __launch_bounds__(256, 2)
void gemm_dual_kernel(const unsigned short* __restrict__ xbf,
                      const unsigned short* __restrict__ wxT,
                      const unsigned short* __restrict__ wyT,
                      const float* __restrict__ bx, const float* __restrict__ by,
                      unsigned short* __restrict__ xbp, unsigned short* __restrict__ ybuf) {
  __shared__ __align__(16) unsigned short As[128 * 32];
  __shared__ __align__(16) unsigned short Bs0[128 * 32];
  __shared__ __align__(16) unsigned short Bs1[128 * 32];
  const int tid = threadIdx.x, lane = tid & 63, wv = tid >> 6;
  const int m0 = blockIdx.y * 128, n0 = blockIdx.x * 128;
  const int sr = lane >> 2, sk = (lane & 3) * 8;
  const int wm = (wv >> 1) << 6, wn = (wv & 1) << 6;
  const int fm = lane & 15, fq = lane >> 4;

  f32x4 acc0[4][4], acc1[4][4];
#pragma unroll
  for (int i = 0; i < 4; ++i)
#pragma unroll
    for (int j = 0; j < 4; ++j) {
      acc0[i][j] = f32x4{0.f, 0.f, 0.f, 0.f};
      acc1[i][j] = f32x4{0.f, 0.f, 0.f, 0.f};
    }

  const unsigned short* ga  = xbf + (size_t)(m0 + wv * 32 + sr) * 512 + sk;
  const unsigned short* gb0 = wxT + (size_t)(n0 + wv * 32 + sr) * 512 + sk;
  const unsigned short* gb1 = wyT + (size_t)(n0 + wv * 32 + sr) * 512 + sk;
  unsigned short* lA  = &As [wv * 32 * 32];
  unsigned short* lB0 = &Bs0[wv * 32 * 32];
  unsigned short* lB1 = &Bs1[wv * 32 * 32];

  for (int k0 = 0; k0 < 512; k0 += 32) {
    __syncthreads();
    gl2lds16(ga  + k0,            lA);
    gl2lds16(ga  + k0 + 16 * 512, lA  + 16 * 32);
    gl2lds16(gb0 + k0,            lB0);
    gl2lds16(gb0 + k0 + 16 * 512, lB0 + 16 * 32);
    gl2lds16(gb1 + k0,            lB1);
    gl2lds16(gb1 + k0 + 16 * 512, lB1 + 16 * 32);
    __syncthreads();
    bf16x8 af[4], bfr0[4], bfr1[4];
#pragma unroll
    for (int i = 0; i < 4; ++i)
      af[i] = *(const bf16x8*)&As[(wm + i * 16 + fm) * 32 + fq * 8];
#pragma unroll
    for (int j = 0; j < 4; ++j) {
      bfr0[j] = *(const bf16x8*)&Bs0[(wn + j * 16 + fm) * 32 + fq * 8];
      bfr1[j] = *(const bf16x8*)&Bs1[(wn + j * 16 + fm) * 32 + fq * 8];
    }
#pragma unroll
    for (int i = 0; i < 4; ++i)
#pragma unroll
      for (int j = 0; j < 4; ++j) {
        acc0[i][j] = __builtin_amdgcn_mfma_f32_16x16x32_bf16(af[i], bfr0[j], acc0[i][j], 0, 0, 0);
        acc1[i][j] = __builtin_amdgcn_mfma_f32_16x16x32_bf16(af[i], bfr1[j], acc1[i][j], 0, 0, 0);
      }
  }
#pragma unroll
  for (int i = 0; i < 4; ++i) {
#pragma unroll
    for (int j = 0; j < 4; ++j) {
      int col = n0 + wn + j * 16 + fm;
      float bxv = bx[col], byv = by[col];
#pragma unroll
      for (int r = 0; r < 4; ++r) {
        int row = m0 + wm + i * 16 + fq * 4 + r;
        size_t idx = (size_t)row * 512 + col;
        xbp[idx] = f2bf(acc0[i][j][r] + bxv);
        float z = acc1[i][j][r] + byv;
        float zc = 0.7978845608028654f * (z + 0.044715f * z * z * z);
        float e = fexp(2.0f * zc);                       // fast tanh: 1 - 2/(e^{2t}+1)
        float th = 1.0f - 2.0f * frcp(e + 1.0f);
        ybuf[idx] = f2bf(0.5f * z * (1.0f + th));
      }
    }
  }
}

// ---------------- conv (TW=4) + MFMA gate GEMMs + fast-math epilogue
// ISOLATION EXPERIMENT: round-0 structure (scattered epilogue stores, separate
// scan1) with ONLY the LDS shrink applied: 53760 -> 36864 B via register-carried
// conv outputs + xin/xc union => 4 blocks/CU instead of 3.
#define XP 72
__global__ __launch_bounds__(256, 4)
void conv_gates_kernel(const unsigned short* __restrict__ xbp,
                       const unsigned char* __restrict__ reset,
                       const float* __restrict__ conv_w, const float* __restrict__ conv_b,
                       const float* __restrict__ spbuf,
                       const unsigned short* __restrict__ wiTH, const unsigned short* __restrict__ wiTL,
                       const unsigned short* __restrict__ waTH, const unsigned short* __restrict__ waTL,
                       const float* __restrict__ bi, const float* __restrict__ ba,
                       unsigned short* __restrict__ aq_out, unsigned short* __restrict__ nrm) {
  __shared__ __align__(16) unsigned short lds[2 * 128 * XP];
  unsigned short* xin = lds;            // 131*64 u16, valid until 2nd sync
  unsigned short* xcH = lds;            // 128*XP, written after xin is dead
  unsigned short* xcL = lds + 128 * XP;
  const int tile = blockIdx.x, h = blockIdx.y, b = blockIdx.z;
  const int t0 = tile << 7;
  const int tid = threadIdx.x, lane = tid & 63, wv = tid >> 6;
  const int fm = lane & 15, fq = lane >> 4;

  // vectorized staging: 131 rows x 64 ch = 1048 u16x8 groups
  const size_t cb0 = ((size_t)b * 2048) * 512 + (h << 6);
  for (int idx = tid; idx < 1048; idx += 256) {
    int row = idx >> 3, c8 = (idx & 7) << 3;
    int t = t0 - 3 + row;
    u16x8 v = u16x8{0, 0, 0, 0, 0, 0, 0, 0};
    if (t >= 0) v = *(const u16x8*)(xbp + cb0 + (size_t)t * 512 + c8);
    *(u16x8*)&xin[row * 64 + c8] = v;
  }
  __syncthreads();
  // vectorized conv in fp32 -> hi/lo bf16 held in REGISTERS across the sync
  u16x8 ohr[4], olr[4];
  const int cc8 = (tid & 7) << 3, u0 = tid >> 3;
  {
    const int ch8 = (h << 6) + cc8;
    float cw[4][8], cbv[8];
#pragma unroll
    for (int s = 0; s < 4; ++s) {
      *(float4*)&cw[s][0] = *(const float4*)(conv_w + s * 512 + ch8);
      *(float4*)&cw[s][4] = *(const float4*)(conv_w + s * 512 + ch8 + 4);
    }
    *(float4*)&cbv[0] = *(const float4*)(conv_b + ch8);
    *(float4*)&cbv[4] = *(const float4*)(conv_b + ch8 + 4);
#pragma unroll
    for (int g = 0; g < 4; ++g) {
      int u = u0 + g * 32;
      u16x8 r0 = *(const u16x8*)&xin[(u + 0) * 64 + cc8];
      u16x8 r1 = *(const u16x8*)&xin[(u + 1) * 64 + cc8];
      u16x8 r2 = *(const u16x8*)&xin[(u + 2) * 64 + cc8];
      u16x8 r3 = *(const u16x8*)&xin[(u + 3) * 64 + cc8];
      u16x8 oh, ol;
#pragma unroll
      for (int j = 0; j < 8; ++j) {
        float v = cbv[j] + cw[0][j] * bf2f(r0[j]) + cw[1][j] * bf2f(r1[j]) +
                  cw[2][j] * bf2f(r2[j]) + cw[3][j] * bf2f(r3[j]);
        oh[j] = f2bf(v);
        ol[j] = f2bf(v - bf2f(oh[j]));
      }
      ohr[g] = oh; olr[g] = ol;
    }
  }
  __syncthreads();                      // all xin reads complete; region reusable
#pragma unroll
  for (int g = 0; g < 4; ++g) {
    int u = u0 + g * 32;
    *(u16x8*)&xcH[u * XP + cc8] = ohr[g];
    *(u16x8*)&xcL[u * XP + cc8] = olr[g];
  }
  // B fragments (wave-invariant; issued before the sync to overlap)
  bf16x8 bIh[4][2], bIl[4][2], bAh[4][2], bAl[4][2];
#pragma unroll
  for (int nt = 0; nt < 4; ++nt)
#pragma unroll
    for (int ks = 0; ks < 2; ++ks) {
      size_t off = (size_t)h * 4096 + (size_t)(nt * 16 + fm) * 64 + ks * 32 + fq * 8;
      bIh[nt][ks] = *(const bf16x8*)(wiTH + off);
      bIl[nt][ks] = *(const bf16x8*)(wiTL + off);
      bAh[nt][ks] = *(const bf16x8*)(waTH + off);
      bAl[nt][ks] = *(const bf16x8*)(waTL + off);
    }
  f32x4 accI[2][4], accA[2][4];
#pragma unroll
  for (int mt = 0; mt < 2; ++mt)
#pragma unroll
    for (int nt = 0; nt < 4; ++nt) {
      accI[mt][nt] = f32x4{0.f, 0.f, 0.f, 0.f};
      accA[mt][nt] = f32x4{0.f, 0.f, 0.f, 0.f};
    }
  __syncthreads();                      // xc planes ready
#pragma unroll
  for (int mt = 0; mt < 2; ++mt) {
    int mrow = wv * 32 + mt * 16 + fm;
#pragma unroll
    for (int ks = 0; ks < 2; ++ks) {
      bf16x8 ah = *(const bf16x8*)&xcH[mrow * XP + ks * 32 + fq * 8];
      bf16x8 al = *(const bf16x8*)&xcL[mrow * XP + ks * 32 + fq * 8];
#pragma unroll
      for (int nt = 0; nt < 4; ++nt) {
        accI[mt][nt] = __builtin_amdgcn_mfma_f32_16x16x32_bf16(ah, bIh[nt][ks], accI[mt][nt], 0, 0, 0);
        accI[mt][nt] = __builtin_amdgcn_mfma_f32_16x16x32_bf16(ah, bIl[nt][ks], accI[mt][nt], 0, 0, 0);
        accI[mt][nt] = __builtin_amdgcn_mfma_f32_16x16x32_bf16(al, bIh[nt][ks], accI[mt][nt], 0, 0, 0);
        accA[mt][nt] = __builtin_amdgcn_mfma_f32_16x16x32_bf16(ah, bAh[nt][ks], accA[mt][nt], 0, 0, 0);
        accA[mt][nt] = __builtin_amdgcn_mfma_f32_16x16x32_bf16(ah, bAl[nt][ks], accA[mt][nt], 0, 0, 0);
        accA[mt][nt] = __builtin_amdgcn_mfma_f32_16x16x32_bf16(al, bAh[nt][ks], accA[mt][nt], 0, 0, 0);
      }
    }
  }
  // epilogue: all-native-transcendental (round-0 scattered stores)
#pragma unroll
  for (int nt = 0; nt < 4; ++nt) {
    int colg = (h << 6) + nt * 16 + fm;
    float biv = bi[colg], bav = ba[colg];
    float sp8 = -8.0f * spbuf[colg];
#pragma unroll
    for (int mt = 0; mt < 2; ++mt) {
#pragma unroll
      for (int r = 0; r < 4; ++r) {
        int mrow = wv * 32 + mt * 16 + fq * 4 + r;
        int t = t0 + mrow;
        float xcv = bf2f(xcH[mrow * XP + nt * 16 + fm]) + bf2f(xcL[mrow * XP + nt * 16 + fm]);
        float gx = frcp(1.0f + fexp(-(accI[mt][nt][r] + biv)));
        float ga = frcp(1.0f + fexp(-(accA[mt][nt][r] + bav)));
        float la = sp8 * ga;
        float av = fexp(la);
        float mult = __builtin_amdgcn_sqrtf(fmaxf(1.0f - fexp(2.0f * la), 0.0f));
        if (reset[b * 2048 + t]) { mult = 1.0f; av = 0.0f; }
        size_t idx = ((size_t)(b * 2048 + t)) * 512 + colg;
        aq_out[idx] = (unsigned short)fminf(av * 65536.0f + 0.5f, 65535.0f);
        nrm[idx] = f2bf(xcv * gx * mult);
      }
    }
  }
}

// ---------------- chunked linear scan (a as u16 fixed-point, 4 ch/thread)
__global__ void scan1_kernel(const unsigned short* __restrict__ aq, const unsigned short* __restrict__ nrm,
                             float* __restrict__ cA, float* __restrict__ cH) {
  int g = blockIdx.x * 256 + threadIdx.x;  // 131072
  int c4 = (g & 127) << 2, k = (g >> 7) & 31, b = g >> 12;
  size_t base = ((size_t)(b * 2048 + k * 64)) * 512 + c4;
  float A[4] = {1.f, 1.f, 1.f, 1.f}, h[4] = {0.f, 0.f, 0.f, 0.f};
#pragma unroll 4
  for (int i = 0; i < 64; ++i) {
    u16x4 av = *(const u16x4*)(aq + base + (size_t)i * 512);
    u16x4 nv = *(const u16x4*)(nrm + base + (size_t)i * 512);
#pragma unroll
    for (int j = 0; j < 4; ++j) {
      float a = (float)av[j] * (1.0f / 65536.0f);
      A[j] *= a;
      h[j] = fmaf(a, h[j], bf2f(nv[j]));
    }
  }
  int ci = ((b * 32 + k) << 9) + c4;
#pragma unroll
  for (int j = 0; j < 4; ++j) { cA[ci + j] = A[j]; cH[ci + j] = h[j]; }
}

__global__ void scan2_kernel(const float* __restrict__ cA, const float* __restrict__ cH,
                             const float* __restrict__ h0, float* __restrict__ hinit) {
  int b = blockIdx.x, c = threadIdx.x;
  float h = h0[b * 512 + c];
  for (int k = 0; k < 32; ++k) {
    int ci = ((b * 32 + k) << 9) + c;
    hinit[ci] = h;
    h = fmaf(cA[ci], h, cH[ci]);
  }
}

__global__ void scan3_kernel(const unsigned short* __restrict__ aq, const unsigned short* __restrict__ nrm,
                             const float* __restrict__ hinit, const unsigned short* __restrict__ ybuf,
                             unsigned short* __restrict__ p) {
  int g = blockIdx.x * 256 + threadIdx.x;  // 131072
  int c4 = (g & 127) << 2, k = (g >> 7) & 31, b = g >> 12;
  size_t base = ((size_t)(b * 2048 + k * 64)) * 512 + c4;
  int ci = ((b * 32 + k) << 9) + c4;
  float h[4];
#pragma unroll
  for (int j = 0; j < 4; ++j) h[j] = hinit[ci + j];
#pragma unroll 4
  for (int i = 0; i < 64; ++i) {
    u16x4 av = *(const u16x4*)(aq + base + (size_t)i * 512);
    u16x4 nv = *(const u16x4*)(nrm + base + (size_t)i * 512);
    u16x4 yv = *(const u16x4*)(ybuf + base + (size_t)i * 512);
    u16x4 pv;
#pragma unroll
    for (int j = 0; j < 4; ++j) {
      float a = (float)av[j] * (1.0f / 65536.0f);
      h[j] = fmaf(a, h[j], bf2f(nv[j]));
      pv[j] = f2bf(h[j] * bf2f(yv[j]));
    }
    *(u16x4*)(p + base + (size_t)i * 512) = pv;
  }
}

// ---------------- GEMM2: out = p @ w_out + b_out (fp32 out)
__global__ __launch_bounds__(256, 2)
void gemm_out_kernel(const unsigned short* __restrict__ p,
                     const unsigned short* __restrict__ woT,
                     const float* __restrict__ bout, float* __restrict__ out) {
  __shared__ __align__(16) unsigned short As[128 * 32];
  __shared__ __align__(16) unsigned short Bs[128 * 32];
  const int tid = threadIdx.x, lane = tid & 63, wv = tid >> 6;
  const int m0 = blockIdx.y * 128, n0 = blockIdx.x * 128;
  const int sr = lane >> 2, sk = (lane & 3) * 8;
  const int wm = (wv >> 1) << 6, wn = (wv & 1) << 6;
  const int fm = lane & 15, fq = lane >> 4;

  f32x4 acc[4][4];
#pragma unroll
  for (int i = 0; i < 4; ++i)
#pragma unroll
    for (int j = 0; j < 4; ++j) acc[i][j] = f32x4{0.f, 0.f, 0.f, 0.f};

  const unsigned short* ga = p   + (size_t)(m0 + wv * 32 + sr) * 512 + sk;
  const unsigned short* gb = woT + (size_t)(n0 + wv * 32 + sr) * 512 + sk;
  unsigned short* lA = &As[wv * 32 * 32];
  unsigned short* lB = &Bs[wv * 32 * 32];

  for (int k0 = 0; k0 < 512; k0 += 32) {
    __syncthreads();
    gl2lds16(ga + k0,            lA);
    gl2lds16(ga + k0 + 16 * 512, lA + 16 * 32);
    gl2lds16(gb + k0,            lB);
    gl2lds16(gb + k0 + 16 * 512, lB + 16 * 32);
    __syncthreads();
    bf16x8 af[4], bfr[4];
#pragma unroll
    for (int i = 0; i < 4; ++i)
      af[i] = *(const bf16x8*)&As[(wm + i * 16 + fm) * 32 + fq * 8];
#pragma unroll
    for (int j = 0; j < 4; ++j)
      bfr[j] = *(const bf16x8*)&Bs[(wn + j * 16 + fm) * 32 + fq * 8];
#pragma unroll
    for (int i = 0; i < 4; ++i)
#pragma unroll
      for (int j = 0; j < 4; ++j)
        acc[i][j] = __builtin_amdgcn_mfma_f32_16x16x32_bf16(af[i], bfr[j], acc[i][j], 0, 0, 0);
  }
#pragma unroll
  for (int i = 0; i < 4; ++i) {
#pragma unroll
    for (int j = 0; j < 4; ++j) {
      int col = n0 + wn + j * 16 + fm;
      float bv = bout[col];
#pragma unroll
      for (int r = 0; r < 4; ++r) {
        int row = m0 + wm + i * 16 + fq * 4 + r;
        out[(size_t)row * 512 + col] = acc[i][j][r] + bv;
      }
    }
  }
}

extern "C" void kernel_launch(void* const* d_in, const int* in_sizes, int n_in,
                              void* d_out, int out_size, void* d_ws, size_t ws_size,
                              hipStream_t stream) {
  const float* x             = (const float*)d_in[0];
  const unsigned char* reset = (const unsigned char*)d_in[1];
  const float* h0            = (const float*)d_in[2];
  const float* b_x           = (const float*)d_in[4];
  const float* b_y           = (const float*)d_in[6];
  const float* conv_w        = (const float*)d_in[7];
  const float* conv_b        = (const float*)d_in[8];
  const float* bi            = (const float*)d_in[11];
  const float* ba            = (const float*)d_in[13];
  const float* b_out         = (const float*)d_in[15];

  char* ws = (char*)d_ws;
  unsigned short* xbp  = (unsigned short*)(ws);               // 64MB bf16; reused as p
  unsigned short* ybuf = (unsigned short*)(ws + 64 * MBY);    // 64MB bf16
  unsigned short* aq   = (unsigned short*)(ws + 128 * MBY);   // 64MB u16 fixed-point a
  unsigned short* nrm  = (unsigned short*)(ws + 192 * MBY);   // 64MB bf16 (aliases xbf)
  unsigned short* xbf  = (unsigned short*)(ws + 192 * MBY);   // 64MB bf16 x
  float* cA            = (float*)(ws + 256 * MBY);
  float* cH            = (float*)(ws + 258 * MBY);
  float* hinit         = (float*)(ws + 260 * MBY);
  unsigned short* wxT  = (unsigned short*)(ws + 262 * MBY);
  unsigned short* wyT  = (unsigned short*)(ws + 262 * MBY + 524288);
  unsigned short* woT  = (unsigned short*)(ws + 263 * MBY);
  unsigned short* wiTH = (unsigned short*)(ws + 263 * MBY + 524288);
  unsigned short* wiTL = wiTH + 32768;
  unsigned short* waTH = wiTL + 32768;
  unsigned short* waTL = waTH + 32768;
  float* spbuf         = (float*)(waTL + 32768);
  unsigned short* p    = xbp;

  hipLaunchKernelGGL(prep_x_kernel, dim3(32768), dim3(256), 0, stream, x, xbf);
  hipLaunchKernelGGL(prep_misc_kernel, dim3(3202), dim3(256), 0, stream,
                     (const float*)d_in[3], (const float*)d_in[5], (const float*)d_in[14],
                     (const float*)d_in[10], (const float*)d_in[12], (const float*)d_in[9],
                     wxT, wyT, woT, wiTH, wiTL, waTH, waTL, spbuf);
  hipLaunchKernelGGL(gemm_dual_kernel, dim3(4, 512), dim3(256), 0, stream,
                     xbf, wxT, wyT, b_x, b_y, xbp, ybuf);
  hipLaunchKernelGGL(conv_gates_kernel, dim3(16, 8, 32), dim3(256), 0, stream,
                     xbp, reset, conv_w, conv_b, spbuf, wiTH, wiTL, waTH, waTL,
                     bi, ba, aq, nrm);
  hipLaunchKernelGGL(scan1_kernel, dim3(512), dim3(256), 0, stream, aq, nrm, cA, cH);
  hipLaunchKernelGGL(scan2_kernel, dim3(32), dim3(512), 0, stream, cA, cH, h0, hinit);
  hipLaunchKernelGGL(scan3_kernel, dim3(512), dim3(256), 0, stream, aq, nrm, hinit, ybuf, p);
  hipLaunchKernelGGL(gemm_out_kernel, dim3(4, 512), dim3(256), 0, stream, p, woT, b_out, (float*)d_out);
}

// Round 4
// 612.987 us; speedup vs baseline: 1.1595x; 1.1595x over previous
//
#include <hip/hip_runtime.h>

typedef __bf16 bf16x8 __attribute__((ext_vector_type(8)));
typedef float f32x4 __attribute__((ext_vector_type(4)));
typedef unsigned short u16x8 __attribute__((ext_vector_type(8)));
typedef unsigned short u16x4 __attribute__((ext_vector_type(4)));

#define MBY (1ull << 20)

__device__ __forceinline__ unsigned short f2bf(float f) {
  union { float f; unsigned u; } v; v.f = f;
  unsigned r = v.u + 0x7fffu + ((v.u >> 16) & 1u);  // RNE
  return (unsigned short)(r >> 16);
}
__device__ __forceinline__ float bf2f(unsigned short s) {
  union { unsigned u; float f; } v; v.u = ((unsigned)s) << 16;
  return v.f;
}
__device__ __forceinline__ float fexp(float x) {        // native v_exp_f32
  return __builtin_amdgcn_exp2f(x * 1.44269504088896340736f);
}
__device__ __forceinline__ float frcp(float x) {        // native v_rcp_f32 (~1 ulp)
  return __builtin_amdgcn_rcpf(x);
}
// async global->LDS, 16B per lane; lds dest = wave-uniform base + lane*16
__device__ __forceinline__ void gl2lds16(const void* g, void* l) {
  __builtin_amdgcn_global_load_lds(
      (const __attribute__((address_space(1))) unsigned int*)g,
      (__attribute__((address_space(3))) unsigned int*)l, 16, 0, 0);
}

// ---------------- prep: weight transposes + gate hi/lo split + softplus table
__global__ void prep_misc_kernel(const float* __restrict__ wx, const float* __restrict__ wy,
                                 const float* __restrict__ wo,
                                 const float* __restrict__ wi, const float* __restrict__ wa,
                                 const float* __restrict__ a_param,
                                 unsigned short* __restrict__ wxT, unsigned short* __restrict__ wyT,
                                 unsigned short* __restrict__ woT,
                                 unsigned short* __restrict__ wiTH, unsigned short* __restrict__ wiTL,
                                 unsigned short* __restrict__ waTH, unsigned short* __restrict__ waTL,
                                 float* __restrict__ spbuf) {
  int bid = blockIdx.x, tid = threadIdx.x;
  if (bid < 3072) {                       // 3 big weights: transpose+bf16
    int mat = bid >> 10;
    int g = (bid & 1023) * 256 + tid;
    int n = g & 511, k = g >> 9;
    const float* src = (mat == 0) ? wx : (mat == 1) ? wy : wo;
    unsigned short* dst = (mat == 0) ? wxT : (mat == 1) ? wyT : woT;
    dst[(size_t)n * 512 + k] = f2bf(src[(size_t)k * 512 + n]);
  } else if (bid < 3200) {                // gate weights: transposed hi/lo split
    int g = (bid - 3072) * 256 + tid;
    int j = g & 63, i = (g >> 6) & 63, h = g >> 12;
    size_t src = (size_t)h * 4096 + (size_t)i * 64 + j;
    size_t dst = (size_t)h * 4096 + (size_t)j * 64 + i;
    float v = wi[src];
    unsigned short hh = f2bf(v);
    wiTH[dst] = hh; wiTL[dst] = f2bf(v - bf2f(hh));
    v = wa[src];
    hh = f2bf(v);
    waTH[dst] = hh; waTL[dst] = f2bf(v - bf2f(hh));
  } else {                                // softplus(a_param) table (accurate, once)
    int g = (bid - 3200) * 256 + tid;
    if (g < 512) {
      float ap = a_param[g];
      spbuf[g] = (ap > 0.f) ? ap + log1pf(expf(-ap)) : log1pf(expf(ap));
    }
  }
}

// ---------------- GEMM1 (dual): xb_pre = x@w_x + b_x ; yb = gelu(x@w_y + b_y)
// A-operand read directly from f32 x with in-register RNE f2bf conversion
// (replaces the prep_x kernel; bit-identical A fragments).
__global__ __launch_bounds__(256, 2)
void gemm_dual_kernel(const float* __restrict__ x,
                      const unsigned short* __restrict__ wxT,
                      const unsigned short* __restrict__ wyT,
                      const float* __restrict__ bx, const float* __restrict__ by,
                      unsigned short* __restrict__ xbp, unsigned short* __restrict__ ybuf) {
  __shared__ __align__(16) unsigned short As[128 * 32];
  __shared__ __align__(16) unsigned short Bs0[128 * 32];
  __shared__ __align__(16) unsigned short Bs1[128 * 32];
  const int tid = threadIdx.x, lane = tid & 63, wv = tid >> 6;
  const int m0 = blockIdx.y * 128, n0 = blockIdx.x * 128;
  const int sr = lane >> 2, sk = (lane & 3) * 8;
  const int wm = (wv >> 1) << 6, wn = (wv & 1) << 6;
  const int fm = lane & 15, fq = lane >> 4;

  f32x4 acc0[4][4], acc1[4][4];
#pragma unroll
  for (int i = 0; i < 4; ++i)
#pragma unroll
    for (int j = 0; j < 4; ++j) {
      acc0[i][j] = f32x4{0.f, 0.f, 0.f, 0.f};
      acc1[i][j] = f32x4{0.f, 0.f, 0.f, 0.f};
    }

  const float* gaf          = x   + (size_t)(m0 + wv * 32 + sr) * 512 + sk;
  const unsigned short* gb0 = wxT + (size_t)(n0 + wv * 32 + sr) * 512 + sk;
  const unsigned short* gb1 = wyT + (size_t)(n0 + wv * 32 + sr) * 512 + sk;
  unsigned short* lA  = &As [wv * 32 * 32];
  unsigned short* lB0 = &Bs0[wv * 32 * 32];
  unsigned short* lB1 = &Bs1[wv * 32 * 32];

  for (int k0 = 0; k0 < 512; k0 += 32) {
    __syncthreads();
    gl2lds16(gb0 + k0,            lB0);
    gl2lds16(gb0 + k0 + 16 * 512, lB0 + 16 * 32);
    gl2lds16(gb1 + k0,            lB1);
    gl2lds16(gb1 + k0 + 16 * 512, lB1 + 16 * 32);
    {
      float4 a0 = *(const float4*)(gaf + k0);
      float4 a1 = *(const float4*)(gaf + k0 + 4);
      float4 a2 = *(const float4*)(gaf + k0 + 16 * 512);
      float4 a3 = *(const float4*)(gaf + k0 + 16 * 512 + 4);
      u16x8 w0, w1;
      w0[0] = f2bf(a0.x); w0[1] = f2bf(a0.y); w0[2] = f2bf(a0.z); w0[3] = f2bf(a0.w);
      w0[4] = f2bf(a1.x); w0[5] = f2bf(a1.y); w0[6] = f2bf(a1.z); w0[7] = f2bf(a1.w);
      w1[0] = f2bf(a2.x); w1[1] = f2bf(a2.y); w1[2] = f2bf(a2.z); w1[3] = f2bf(a2.w);
      w1[4] = f2bf(a3.x); w1[5] = f2bf(a3.y); w1[6] = f2bf(a3.z); w1[7] = f2bf(a3.w);
      *(u16x8*)&lA[sr * 32 + sk]        = w0;
      *(u16x8*)&lA[(sr + 16) * 32 + sk] = w1;
    }
    __syncthreads();
    bf16x8 af[4], bfr0[4], bfr1[4];
#pragma unroll
    for (int i = 0; i < 4; ++i)
      af[i] = *(const bf16x8*)&As[(wm + i * 16 + fm) * 32 + fq * 8];
#pragma unroll
    for (int j = 0; j < 4; ++j) {
      bfr0[j] = *(const bf16x8*)&Bs0[(wn + j * 16 + fm) * 32 + fq * 8];
      bfr1[j] = *(const bf16x8*)&Bs1[(wn + j * 16 + fm) * 32 + fq * 8];
    }
#pragma unroll
    for (int i = 0; i < 4; ++i)
#pragma unroll
      for (int j = 0; j < 4; ++j) {
        acc0[i][j] = __builtin_amdgcn_mfma_f32_16x16x32_bf16(af[i], bfr0[j], acc0[i][j], 0, 0, 0);
        acc1[i][j] = __builtin_amdgcn_mfma_f32_16x16x32_bf16(af[i], bfr1[j], acc1[i][j], 0, 0, 0);
      }
  }
#pragma unroll
  for (int i = 0; i < 4; ++i) {
#pragma unroll
    for (int j = 0; j < 4; ++j) {
      int col = n0 + wn + j * 16 + fm;
      float bxv = bx[col], byv = by[col];
#pragma unroll
      for (int r = 0; r < 4; ++r) {
        int row = m0 + wm + i * 16 + fq * 4 + r;
        size_t idx = (size_t)row * 512 + col;
        xbp[idx] = f2bf(acc0[i][j][r] + bxv);
        float z = acc1[i][j][r] + byv;
        float zc = 0.7978845608028654f * (z + 0.044715f * z * z * z);
        float e = fexp(2.0f * zc);                       // fast tanh: 1 - 2/(e^{2t}+1)
        float th = 1.0f - 2.0f * frcp(e + 1.0f);
        ybuf[idx] = f2bf(0.5f * z * (1.0f + th));
      }
    }
  }
}

// ---------------- conv (TW=4) + MFMA gate GEMMs + fast-math epilogue
// EXACT round-0 configuration: 53760 B LDS, 3 blocks/CU. 4-blocks/CU variants
// (r1-r3) all inflated HBM traffic 3-4x via L2/L3 thrash — do not raise.
#define XP 72
__global__ __launch_bounds__(256, 2)
void conv_gates_kernel(const unsigned short* __restrict__ xbp,
                       const unsigned char* __restrict__ reset,
                       const float* __restrict__ conv_w, const float* __restrict__ conv_b,
                       const float* __restrict__ spbuf,
                       const unsigned short* __restrict__ wiTH, const unsigned short* __restrict__ wiTL,
                       const unsigned short* __restrict__ waTH, const unsigned short* __restrict__ waTL,
                       const float* __restrict__ bi, const float* __restrict__ ba,
                       unsigned short* __restrict__ aq_out, unsigned short* __restrict__ nrm) {
  __shared__ __align__(16) unsigned short xin[131 * 64];
  __shared__ __align__(16) unsigned short xcH[128 * XP];
  __shared__ __align__(16) unsigned short xcL[128 * XP];
  const int tile = blockIdx.x, h = blockIdx.y, b = blockIdx.z;
  const int t0 = tile << 7;
  const int tid = threadIdx.x, lane = tid & 63, wv = tid >> 6;
  const int fm = lane & 15, fq = lane >> 4;

  // vectorized staging: 131 rows x 64 ch = 1048 u16x8 groups
  const size_t cb0 = ((size_t)b * 2048) * 512 + (h << 6);
  for (int idx = tid; idx < 1048; idx += 256) {
    int row = idx >> 3, c8 = (idx & 7) << 3;
    int t = t0 - 3 + row;
    u16x8 v = u16x8{0, 0, 0, 0, 0, 0, 0, 0};
    if (t >= 0) v = *(const u16x8*)(xbp + cb0 + (size_t)t * 512 + c8);
    *(u16x8*)&xin[row * 64 + c8] = v;
  }
  __syncthreads();
  // vectorized conv in fp32 -> hi/lo bf16 planes
  {
    const int c8 = (tid & 7) << 3, u0 = tid >> 3;
    const int ch8 = (h << 6) + c8;
    float cw[4][8], cbv[8];
#pragma unroll
    for (int s = 0; s < 4; ++s) {
      *(float4*)&cw[s][0] = *(const float4*)(conv_w + s * 512 + ch8);
      *(float4*)&cw[s][4] = *(const float4*)(conv_w + s * 512 + ch8 + 4);
    }
    *(float4*)&cbv[0] = *(const float4*)(conv_b + ch8);
    *(float4*)&cbv[4] = *(const float4*)(conv_b + ch8 + 4);
#pragma unroll
    for (int g = 0; g < 4; ++g) {
      int u = u0 + g * 32;
      u16x8 r0 = *(const u16x8*)&xin[(u + 0) * 64 + c8];
      u16x8 r1 = *(const u16x8*)&xin[(u + 1) * 64 + c8];
      u16x8 r2 = *(const u16x8*)&xin[(u + 2) * 64 + c8];
      u16x8 r3 = *(const u16x8*)&xin[(u + 3) * 64 + c8];
      u16x8 oh, ol;
#pragma unroll
      for (int j = 0; j < 8; ++j) {
        float v = cbv[j] + cw[0][j] * bf2f(r0[j]) + cw[1][j] * bf2f(r1[j]) +
                  cw[2][j] * bf2f(r2[j]) + cw[3][j] * bf2f(r3[j]);
        oh[j] = f2bf(v);
        ol[j] = f2bf(v - bf2f(oh[j]));
      }
      *(u16x8*)&xcH[u * XP + c8] = oh;
      *(u16x8*)&xcL[u * XP + c8] = ol;
    }
  }
  // B fragments (wave-invariant, cached)
  bf16x8 bIh[4][2], bIl[4][2], bAh[4][2], bAl[4][2];
#pragma unroll
  for (int nt = 0; nt < 4; ++nt)
#pragma unroll
    for (int ks = 0; ks < 2; ++ks) {
      size_t off = (size_t)h * 4096 + (size_t)(nt * 16 + fm) * 64 + ks * 32 + fq * 8;
      bIh[nt][ks] = *(const bf16x8*)(wiTH + off);
      bIl[nt][ks] = *(const bf16x8*)(wiTL + off);
      bAh[nt][ks] = *(const bf16x8*)(waTH + off);
      bAl[nt][ks] = *(const bf16x8*)(waTL + off);
    }
  f32x4 accI[2][4], accA[2][4];
#pragma unroll
  for (int mt = 0; mt < 2; ++mt)
#pragma unroll
    for (int nt = 0; nt < 4; ++nt) {
      accI[mt][nt] = f32x4{0.f, 0.f, 0.f, 0.f};
      accA[mt][nt] = f32x4{0.f, 0.f, 0.f, 0.f};
    }
  __syncthreads();
#pragma unroll
  for (int mt = 0; mt < 2; ++mt) {
    int mrow = wv * 32 + mt * 16 + fm;
#pragma unroll
    for (int ks = 0; ks < 2; ++ks) {
      bf16x8 ah = *(const bf16x8*)&xcH[mrow * XP + ks * 32 + fq * 8];
      bf16x8 al = *(const bf16x8*)&xcL[mrow * XP + ks * 32 + fq * 8];
#pragma unroll
      for (int nt = 0; nt < 4; ++nt) {
        accI[mt][nt] = __builtin_amdgcn_mfma_f32_16x16x32_bf16(ah, bIh[nt][ks], accI[mt][nt], 0, 0, 0);
        accI[mt][nt] = __builtin_amdgcn_mfma_f32_16x16x32_bf16(ah, bIl[nt][ks], accI[mt][nt], 0, 0, 0);
        accI[mt][nt] = __builtin_amdgcn_mfma_f32_16x16x32_bf16(al, bIh[nt][ks], accI[mt][nt], 0, 0, 0);
        accA[mt][nt] = __builtin_amdgcn_mfma_f32_16x16x32_bf16(ah, bAh[nt][ks], accA[mt][nt], 0, 0, 0);
        accA[mt][nt] = __builtin_amdgcn_mfma_f32_16x16x32_bf16(ah, bAl[nt][ks], accA[mt][nt], 0, 0, 0);
        accA[mt][nt] = __builtin_amdgcn_mfma_f32_16x16x32_bf16(al, bAh[nt][ks], accA[mt][nt], 0, 0, 0);
      }
    }
  }
  // epilogue: all-native-transcendental
#pragma unroll
  for (int nt = 0; nt < 4; ++nt) {
    int colg = (h << 6) + nt * 16 + fm;
    float biv = bi[colg], bav = ba[colg];
    float sp8 = -8.0f * spbuf[colg];
#pragma unroll
    for (int mt = 0; mt < 2; ++mt) {
#pragma unroll
      for (int r = 0; r < 4; ++r) {
        int mrow = wv * 32 + mt * 16 + fq * 4 + r;
        int t = t0 + mrow;
        float xcv = bf2f(xcH[mrow * XP + nt * 16 + fm]) + bf2f(xcL[mrow * XP + nt * 16 + fm]);
        float gx = frcp(1.0f + fexp(-(accI[mt][nt][r] + biv)));
        float ga = frcp(1.0f + fexp(-(accA[mt][nt][r] + bav)));
        float la = sp8 * ga;
        float av = fexp(la);
        float mult = __builtin_amdgcn_sqrtf(fmaxf(1.0f - fexp(2.0f * la), 0.0f));
        if (reset[b * 2048 + t]) { mult = 1.0f; av = 0.0f; }
        size_t idx = ((size_t)(b * 2048 + t)) * 512 + colg;
        aq_out[idx] = (unsigned short)fminf(av * 65536.0f + 0.5f, 65535.0f);
        nrm[idx] = f2bf(xcv * gx * mult);
      }
    }
  }
}

// ---------------- chunked linear scan (a as u16 fixed-point, 4 ch/thread)
__global__ void scan1_kernel(const unsigned short* __restrict__ aq, const unsigned short* __restrict__ nrm,
                             float* __restrict__ cA, float* __restrict__ cH) {
  int g = blockIdx.x * 256 + threadIdx.x;  // 131072
  int c4 = (g & 127) << 2, k = (g >> 7) & 31, b = g >> 12;
  size_t base = ((size_t)(b * 2048 + k * 64)) * 512 + c4;
  float A[4] = {1.f, 1.f, 1.f, 1.f}, h[4] = {0.f, 0.f, 0.f, 0.f};
#pragma unroll 4
  for (int i = 0; i < 64; ++i) {
    u16x4 av = *(const u16x4*)(aq + base + (size_t)i * 512);
    u16x4 nv = *(const u16x4*)(nrm + base + (size_t)i * 512);
#pragma unroll
    for (int j = 0; j < 4; ++j) {
      float a = (float)av[j] * (1.0f / 65536.0f);
      A[j] *= a;
      h[j] = fmaf(a, h[j], bf2f(nv[j]));
    }
  }
  int ci = ((b * 32 + k) << 9) + c4;
#pragma unroll
  for (int j = 0; j < 4; ++j) { cA[ci + j] = A[j]; cH[ci + j] = h[j]; }
}

__global__ void scan2_kernel(const float* __restrict__ cA, const float* __restrict__ cH,
                             const float* __restrict__ h0, float* __restrict__ hinit) {
  int b = blockIdx.x, c = threadIdx.x;
  float h = h0[b * 512 + c];
  for (int k = 0; k < 32; ++k) {
    int ci = ((b * 32 + k) << 9) + c;
    hinit[ci] = h;
    h = fmaf(cA[ci], h, cH[ci]);
  }
}

__global__ void scan3_kernel(const unsigned short* __restrict__ aq, const unsigned short* __restrict__ nrm,
                             const float* __restrict__ hinit, const unsigned short* __restrict__ ybuf,
                             unsigned short* __restrict__ p) {
  int g = blockIdx.x * 256 + threadIdx.x;  // 131072
  int c4 = (g & 127) << 2, k = (g >> 7) & 31, b = g >> 12;
  size_t base = ((size_t)(b * 2048 + k * 64)) * 512 + c4;
  int ci = ((b * 32 + k) << 9) + c4;
  float h[4];
#pragma unroll
  for (int j = 0; j < 4; ++j) h[j] = hinit[ci + j];
#pragma unroll 4
  for (int i = 0; i < 64; ++i) {
    u16x4 av = *(const u16x4*)(aq + base + (size_t)i * 512);
    u16x4 nv = *(const u16x4*)(nrm + base + (size_t)i * 512);
    u16x4 yv = *(const u16x4*)(ybuf + base + (size_t)i * 512);
    u16x4 pv;
#pragma unroll
    for (int j = 0; j < 4; ++j) {
      float a = (float)av[j] * (1.0f / 65536.0f);
      h[j] = fmaf(a, h[j], bf2f(nv[j]));
      pv[j] = f2bf(h[j] * bf2f(yv[j]));
    }
    *(u16x4*)(p + base + (size_t)i * 512) = pv;
  }
}

// ---------------- GEMM2: out = p @ w_out + b_out (fp32 out)
__global__ __launch_bounds__(256, 2)
void gemm_out_kernel(const unsigned short* __restrict__ p,
                     const unsigned short* __restrict__ woT,
                     const float* __restrict__ bout, float* __restrict__ out) {
  __shared__ __align__(16) unsigned short As[128 * 32];
  __shared__ __align__(16) unsigned short Bs[128 * 32];
  const int tid = threadIdx.x, lane = tid & 63, wv = tid >> 6;
  const int m0 = blockIdx.y * 128, n0 = blockIdx.x * 128;
  const int sr = lane >> 2, sk = (lane & 3) * 8;
  const int wm = (wv >> 1) << 6, wn = (wv & 1) << 6;
  const int fm = lane & 15, fq = lane >> 4;

  f32x4 acc[4][4];
#pragma unroll
  for (int i = 0; i < 4; ++i)
#pragma unroll
    for (int j = 0; j < 4; ++j) acc[i][j] = f32x4{0.f, 0.f, 0.f, 0.f};

  const unsigned short* ga = p   + (size_t)(m0 + wv * 32 + sr) * 512 + sk;
  const unsigned short* gb = woT + (size_t)(n0 + wv * 32 + sr) * 512 + sk;
  unsigned short* lA = &As[wv * 32 * 32];
  unsigned short* lB = &Bs[wv * 32 * 32];

  for (int k0 = 0; k0 < 512; k0 += 32) {
    __syncthreads();
    gl2lds16(ga + k0,            lA);
    gl2lds16(ga + k0 + 16 * 512, lA + 16 * 32);
    gl2lds16(gb + k0,            lB);
    gl2lds16(gb + k0 + 16 * 512, lB + 16 * 32);
    __syncthreads();
    bf16x8 af[4], bfr[4];
#pragma unroll
    for (int i = 0; i < 4; ++i)
      af[i] = *(const bf16x8*)&As[(wm + i * 16 + fm) * 32 + fq * 8];
#pragma unroll
    for (int j = 0; j < 4; ++j)
      bfr[j] = *(const bf16x8*)&Bs[(wn + j * 16 + fm) * 32 + fq * 8];
#pragma unroll
    for (int i = 0; i < 4; ++i)
#pragma unroll
      for (int j = 0; j < 4; ++j)
        acc[i][j] = __builtin_amdgcn_mfma_f32_16x16x32_bf16(af[i], bfr[j], acc[i][j], 0, 0, 0);
  }
#pragma unroll
  for (int i = 0; i < 4; ++i) {
#pragma unroll
    for (int j = 0; j < 4; ++j) {
      int col = n0 + wn + j * 16 + fm;
      float bv = bout[col];
#pragma unroll
      for (int r = 0; r < 4; ++r) {
        int row = m0 + wm + i * 16 + fq * 4 + r;
        out[(size_t)row * 512 + col] = acc[i][j][r] + bv;
      }
    }
  }
}

extern "C" void kernel_launch(void* const* d_in, const int* in_sizes, int n_in,
                              void* d_out, int out_size, void* d_ws, size_t ws_size,
                              hipStream_t stream) {
  const float* x             = (const float*)d_in[0];
  const unsigned char* reset = (const unsigned char*)d_in[1];
  const float* h0            = (const float*)d_in[2];
  const float* b_x           = (const float*)d_in[4];
  const float* b_y           = (const float*)d_in[6];
  const float* conv_w        = (const float*)d_in[7];
  const float* conv_b        = (const float*)d_in[8];
  const float* bi            = (const float*)d_in[11];
  const float* ba            = (const float*)d_in[13];
  const float* b_out         = (const float*)d_in[15];

  char* ws = (char*)d_ws;
  unsigned short* xbp  = (unsigned short*)(ws);               // 64MB bf16; reused as p
  unsigned short* ybuf = (unsigned short*)(ws + 64 * MBY);    // 64MB bf16
  unsigned short* aq   = (unsigned short*)(ws + 128 * MBY);   // 64MB u16 fixed-point a
  unsigned short* nrm  = (unsigned short*)(ws + 192 * MBY);   // 64MB bf16
  float* cA            = (float*)(ws + 256 * MBY);
  float* cH            = (float*)(ws + 258 * MBY);
  float* hinit         = (float*)(ws + 260 * MBY);
  unsigned short* wxT  = (unsigned short*)(ws + 262 * MBY);
  unsigned short* wyT  = (unsigned short*)(ws + 262 * MBY + 524288);
  unsigned short* woT  = (unsigned short*)(ws + 263 * MBY);
  unsigned short* wiTH = (unsigned short*)(ws + 263 * MBY + 524288);
  unsigned short* wiTL = wiTH + 32768;
  unsigned short* waTH = wiTL + 32768;
  unsigned short* waTL = waTH + 32768;
  float* spbuf         = (float*)(waTL + 32768);
  unsigned short* p    = xbp;

  hipLaunchKernelGGL(prep_misc_kernel, dim3(3202), dim3(256), 0, stream,
                     (const float*)d_in[3], (const float*)d_in[5], (const float*)d_in[14],
                     (const float*)d_in[10], (const float*)d_in[12], (const float*)d_in[9],
                     wxT, wyT, woT, wiTH, wiTL, waTH, waTL, spbuf);
  hipLaunchKernelGGL(gemm_dual_kernel, dim3(4, 512), dim3(256), 0, stream,
                     x, wxT, wyT, b_x, b_y, xbp, ybuf);
  hipLaunchKernelGGL(conv_gates_kernel, dim3(16, 8, 32), dim3(256), 0, stream,
                     xbp, reset, conv_w, conv_b, spbuf, wiTH, wiTL, waTH, waTL,
                     bi, ba, aq, nrm);
  hipLaunchKernelGGL(scan1_kernel, dim3(512), dim3(256), 0, stream, aq, nrm, cA, cH);
  hipLaunchKernelGGL(scan2_kernel, dim3(32), dim3(512), 0, stream, cA, cH, h0, hinit);
  hipLaunchKernelGGL(scan3_kernel, dim3(512), dim3(256), 0, stream, aq, nrm, hinit, ybuf, p);
  hipLaunchKernelGGL(gemm_out_kernel, dim3(4, 512), dim3(256), 0, stream, p, woT, b_out, (float*)d_out);
}

// Round 5
// 588.270 us; speedup vs baseline: 1.2082x; 1.0420x over previous
//
#include <hip/hip_runtime.h>

typedef __bf16 bf16x8 __attribute__((ext_vector_type(8)));
typedef float f32x4 __attribute__((ext_vector_type(4)));
typedef unsigned short u16x8 __attribute__((ext_vector_type(8)));
typedef unsigned short u16x4 __attribute__((ext_vector_type(4)));

#define MBY (1ull << 20)

__device__ __forceinline__ unsigned short f2bf(float f) {
  union { float f; unsigned u; } v; v.f = f;
  unsigned r = v.u + 0x7fffu + ((v.u >> 16) & 1u);  // RNE
  return (unsigned short)(r >> 16);
}
__device__ __forceinline__ float bf2f(unsigned short s) {
  union { unsigned u; float f; } v; v.u = ((unsigned)s) << 16;
  return v.f;
}
__device__ __forceinline__ float fexp(float x) {        // native v_exp_f32
  return __builtin_amdgcn_exp2f(x * 1.44269504088896340736f);
}
__device__ __forceinline__ float frcp(float x) {        // native v_rcp_f32 (~1 ulp)
  return __builtin_amdgcn_rcpf(x);
}
// async global->LDS, 16B per lane; lds dest = wave-uniform base + lane*16
__device__ __forceinline__ void gl2lds16(const void* g, void* l) {
  __builtin_amdgcn_global_load_lds(
      (const __attribute__((address_space(1))) unsigned int*)g,
      (__attribute__((address_space(3))) unsigned int*)l, 16, 0, 0);
}

// ---------------- prep: weight transposes + gate hi/lo split + softplus table
__global__ void prep_misc_kernel(const float* __restrict__ wx, const float* __restrict__ wy,
                                 const float* __restrict__ wo,
                                 const float* __restrict__ wi, const float* __restrict__ wa,
                                 const float* __restrict__ a_param,
                                 unsigned short* __restrict__ wxT, unsigned short* __restrict__ wyT,
                                 unsigned short* __restrict__ woT,
                                 unsigned short* __restrict__ wiTH, unsigned short* __restrict__ wiTL,
                                 unsigned short* __restrict__ waTH, unsigned short* __restrict__ waTL,
                                 float* __restrict__ spbuf) {
  int bid = blockIdx.x, tid = threadIdx.x;
  if (bid < 3072) {                       // 3 big weights: transpose+bf16
    int mat = bid >> 10;
    int g = (bid & 1023) * 256 + tid;
    int n = g & 511, k = g >> 9;
    const float* src = (mat == 0) ? wx : (mat == 1) ? wy : wo;
    unsigned short* dst = (mat == 0) ? wxT : (mat == 1) ? wyT : woT;
    dst[(size_t)n * 512 + k] = f2bf(src[(size_t)k * 512 + n]);
  } else if (bid < 3200) {                // gate weights: transposed hi/lo split
    int g = (bid - 3072) * 256 + tid;
    int j = g & 63, i = (g >> 6) & 63, h = g >> 12;
    size_t src = (size_t)h * 4096 + (size_t)i * 64 + j;
    size_t dst = (size_t)h * 4096 + (size_t)j * 64 + i;
    float v = wi[src];
    unsigned short hh = f2bf(v);
    wiTH[dst] = hh; wiTL[dst] = f2bf(v - bf2f(hh));
    v = wa[src];
    hh = f2bf(v);
    waTH[dst] = hh; waTL[dst] = f2bf(v - bf2f(hh));
  } else {                                // softplus(a_param) table (accurate, once)
    int g = (bid - 3200) * 256 + tid;
    if (g < 512) {
      float ap = a_param[g];
      spbuf[g] = (ap > 0.f) ? ap + log1pf(expf(-ap)) : log1pf(expf(ap));
    }
  }
}

// ---------------- GEMM1 (dual): xb_pre = x@w_x + b_x ; yb = gelu(x@w_y + b_y)
// f32 x read directly (prep_x fused). XCD-chunked block swizzle so the 4
// n-blocks of one m-row share an XCD L2. 2 k-steps per barrier round with
// double-buffered LDS halves; next round's A prefetched into regs AFTER the
// second barrier so the ~64 MFMAs cover the load latency.
__global__ __launch_bounds__(256, 2)
void gemm_dual_kernel(const float* __restrict__ x,
                      const unsigned short* __restrict__ wxT,
                      const unsigned short* __restrict__ wyT,
                      const float* __restrict__ bx, const float* __restrict__ by,
                      unsigned short* __restrict__ xbp, unsigned short* __restrict__ ybuf) {
  __shared__ __align__(16) unsigned short As [2 * 128 * 32];
  __shared__ __align__(16) unsigned short Bs0[2 * 128 * 32];
  __shared__ __align__(16) unsigned short Bs1[2 * 128 * 32];
  const int tid = threadIdx.x, lane = tid & 63, wv = tid >> 6;
  const int lg = ((blockIdx.x & 7) << 8) | (blockIdx.x >> 3);   // XCD-chunked, bijective (2048 = 8*256)
  const int m0 = (lg >> 2) << 7, n0 = (lg & 3) << 7;
  const int sr = lane >> 2, sk = (lane & 3) * 8;
  const int wm = (wv >> 1) << 6, wn = (wv & 1) << 6;
  const int fm = lane & 15, fq = lane >> 4;

  f32x4 acc0[4][4], acc1[4][4];
#pragma unroll
  for (int i = 0; i < 4; ++i)
#pragma unroll
    for (int j = 0; j < 4; ++j) {
      acc0[i][j] = f32x4{0.f, 0.f, 0.f, 0.f};
      acc1[i][j] = f32x4{0.f, 0.f, 0.f, 0.f};
    }

  const float* gaf          = x   + (size_t)(m0 + wv * 32 + sr) * 512 + sk;
  const unsigned short* gb0 = wxT + (size_t)(n0 + wv * 32 + sr) * 512 + sk;
  const unsigned short* gb1 = wyT + (size_t)(n0 + wv * 32 + sr) * 512 + sk;
  unsigned short* lA  = As  + wv * 1024;
  unsigned short* lB0 = Bs0 + wv * 1024;
  unsigned short* lB1 = Bs1 + wv * 1024;

  // prologue: prefetch round-0 A
  float4 pa[2][4];
#pragma unroll
  for (int bb = 0; bb < 2; ++bb) {
    pa[bb][0] = *(const float4*)(gaf + bb * 32);
    pa[bb][1] = *(const float4*)(gaf + bb * 32 + 4);
    pa[bb][2] = *(const float4*)(gaf + bb * 32 + 16 * 512);
    pa[bb][3] = *(const float4*)(gaf + bb * 32 + 16 * 512 + 4);
  }

  for (int r = 0; r < 8; ++r) {
    const int k0 = r << 6;
    __syncthreads();
#pragma unroll
    for (int bb = 0; bb < 2; ++bb) {
      gl2lds16(gb0 + k0 + bb * 32,            lB0 + bb * 4096);
      gl2lds16(gb0 + k0 + bb * 32 + 16 * 512, lB0 + bb * 4096 + 512);
      gl2lds16(gb1 + k0 + bb * 32,            lB1 + bb * 4096);
      gl2lds16(gb1 + k0 + bb * 32 + 16 * 512, lB1 + bb * 4096 + 512);
      u16x8 w0, w1;
      w0[0] = f2bf(pa[bb][0].x); w0[1] = f2bf(pa[bb][0].y);
      w0[2] = f2bf(pa[bb][0].z); w0[3] = f2bf(pa[bb][0].w);
      w0[4] = f2bf(pa[bb][1].x); w0[5] = f2bf(pa[bb][1].y);
      w0[6] = f2bf(pa[bb][1].z); w0[7] = f2bf(pa[bb][1].w);
      w1[0] = f2bf(pa[bb][2].x); w1[1] = f2bf(pa[bb][2].y);
      w1[2] = f2bf(pa[bb][2].z); w1[3] = f2bf(pa[bb][2].w);
      w1[4] = f2bf(pa[bb][3].x); w1[5] = f2bf(pa[bb][3].y);
      w1[6] = f2bf(pa[bb][3].z); w1[7] = f2bf(pa[bb][3].w);
      *(u16x8*)&lA[bb * 4096 + sr * 32 + sk] = w0;
      *(u16x8*)&lA[bb * 4096 + sr * 32 + sk + 512] = w1;
    }
    __syncthreads();
    // prefetch next round's A — latency hidden under the 64 MFMAs below
    if (r < 7) {
      const float* g2 = gaf + k0 + 64;
#pragma unroll
      for (int bb = 0; bb < 2; ++bb) {
        pa[bb][0] = *(const float4*)(g2 + bb * 32);
        pa[bb][1] = *(const float4*)(g2 + bb * 32 + 4);
        pa[bb][2] = *(const float4*)(g2 + bb * 32 + 16 * 512);
        pa[bb][3] = *(const float4*)(g2 + bb * 32 + 16 * 512 + 4);
      }
    }
#pragma unroll
    for (int bb = 0; bb < 2; ++bb) {
      const unsigned short* Ab  = As  + bb * 4096;
      const unsigned short* B0b = Bs0 + bb * 4096;
      const unsigned short* B1b = Bs1 + bb * 4096;
      bf16x8 af[4], bfr0[4], bfr1[4];
#pragma unroll
      for (int i = 0; i < 4; ++i)
        af[i] = *(const bf16x8*)&Ab[(wm + i * 16 + fm) * 32 + fq * 8];
#pragma unroll
      for (int j = 0; j < 4; ++j) {
        bfr0[j] = *(const bf16x8*)&B0b[(wn + j * 16 + fm) * 32 + fq * 8];
        bfr1[j] = *(const bf16x8*)&B1b[(wn + j * 16 + fm) * 32 + fq * 8];
      }
#pragma unroll
      for (int i = 0; i < 4; ++i)
#pragma unroll
        for (int j = 0; j < 4; ++j) {
          acc0[i][j] = __builtin_amdgcn_mfma_f32_16x16x32_bf16(af[i], bfr0[j], acc0[i][j], 0, 0, 0);
          acc1[i][j] = __builtin_amdgcn_mfma_f32_16x16x32_bf16(af[i], bfr1[j], acc1[i][j], 0, 0, 0);
        }
    }
  }
#pragma unroll
  for (int i = 0; i < 4; ++i) {
#pragma unroll
    for (int j = 0; j < 4; ++j) {
      int col = n0 + wn + j * 16 + fm;
      float bxv = bx[col], byv = by[col];
#pragma unroll
      for (int r = 0; r < 4; ++r) {
        int row = m0 + wm + i * 16 + fq * 4 + r;
        size_t idx = (size_t)row * 512 + col;
        xbp[idx] = f2bf(acc0[i][j][r] + bxv);
        float z = acc1[i][j][r] + byv;
        float zc = 0.7978845608028654f * (z + 0.044715f * z * z * z);
        float e = fexp(2.0f * zc);                       // fast tanh: 1 - 2/(e^{2t}+1)
        float th = 1.0f - 2.0f * frcp(e + 1.0f);
        ybuf[idx] = f2bf(0.5f * z * (1.0f + th));
      }
    }
  }
}

// ---------------- conv (TW=4) + MFMA gate GEMMs + fast-math epilogue
// EXACT round-0 configuration: 53760 B LDS, 3 blocks/CU. 4-blocks/CU variants
// (r1-r3) all inflated HBM traffic 3-4x via L2/L3 thrash — do not raise.
#define XP 72
__global__ __launch_bounds__(256, 2)
void conv_gates_kernel(const unsigned short* __restrict__ xbp,
                       const unsigned char* __restrict__ reset,
                       const float* __restrict__ conv_w, const float* __restrict__ conv_b,
                       const float* __restrict__ spbuf,
                       const unsigned short* __restrict__ wiTH, const unsigned short* __restrict__ wiTL,
                       const unsigned short* __restrict__ waTH, const unsigned short* __restrict__ waTL,
                       const float* __restrict__ bi, const float* __restrict__ ba,
                       unsigned short* __restrict__ aq_out, unsigned short* __restrict__ nrm) {
  __shared__ __align__(16) unsigned short xin[131 * 64];
  __shared__ __align__(16) unsigned short xcH[128 * XP];
  __shared__ __align__(16) unsigned short xcL[128 * XP];
  const int tile = blockIdx.x, h = blockIdx.y, b = blockIdx.z;
  const int t0 = tile << 7;
  const int tid = threadIdx.x, lane = tid & 63, wv = tid >> 6;
  const int fm = lane & 15, fq = lane >> 4;

  // vectorized staging: 131 rows x 64 ch = 1048 u16x8 groups
  const size_t cb0 = ((size_t)b * 2048) * 512 + (h << 6);
  for (int idx = tid; idx < 1048; idx += 256) {
    int row = idx >> 3, c8 = (idx & 7) << 3;
    int t = t0 - 3 + row;
    u16x8 v = u16x8{0, 0, 0, 0, 0, 0, 0, 0};
    if (t >= 0) v = *(const u16x8*)(xbp + cb0 + (size_t)t * 512 + c8);
    *(u16x8*)&xin[row * 64 + c8] = v;
  }
  __syncthreads();
  // vectorized conv in fp32 -> hi/lo bf16 planes
  {
    const int c8 = (tid & 7) << 3, u0 = tid >> 3;
    const int ch8 = (h << 6) + c8;
    float cw[4][8], cbv[8];
#pragma unroll
    for (int s = 0; s < 4; ++s) {
      *(float4*)&cw[s][0] = *(const float4*)(conv_w + s * 512 + ch8);
      *(float4*)&cw[s][4] = *(const float4*)(conv_w + s * 512 + ch8 + 4);
    }
    *(float4*)&cbv[0] = *(const float4*)(conv_b + ch8);
    *(float4*)&cbv[4] = *(const float4*)(conv_b + ch8 + 4);
#pragma unroll
    for (int g = 0; g < 4; ++g) {
      int u = u0 + g * 32;
      u16x8 r0 = *(const u16x8*)&xin[(u + 0) * 64 + c8];
      u16x8 r1 = *(const u16x8*)&xin[(u + 1) * 64 + c8];
      u16x8 r2 = *(const u16x8*)&xin[(u + 2) * 64 + c8];
      u16x8 r3 = *(const u16x8*)&xin[(u + 3) * 64 + c8];
      u16x8 oh, ol;
#pragma unroll
      for (int j = 0; j < 8; ++j) {
        float v = cbv[j] + cw[0][j] * bf2f(r0[j]) + cw[1][j] * bf2f(r1[j]) +
                  cw[2][j] * bf2f(r2[j]) + cw[3][j] * bf2f(r3[j]);
        oh[j] = f2bf(v);
        ol[j] = f2bf(v - bf2f(oh[j]));
      }
      *(u16x8*)&xcH[u * XP + c8] = oh;
      *(u16x8*)&xcL[u * XP + c8] = ol;
    }
  }
  // B fragments (wave-invariant, cached)
  bf16x8 bIh[4][2], bIl[4][2], bAh[4][2], bAl[4][2];
#pragma unroll
  for (int nt = 0; nt < 4; ++nt)
#pragma unroll
    for (int ks = 0; ks < 2; ++ks) {
      size_t off = (size_t)h * 4096 + (size_t)(nt * 16 + fm) * 64 + ks * 32 + fq * 8;
      bIh[nt][ks] = *(const bf16x8*)(wiTH + off);
      bIl[nt][ks] = *(const bf16x8*)(wiTL + off);
      bAh[nt][ks] = *(const bf16x8*)(waTH + off);
      bAl[nt][ks] = *(const bf16x8*)(waTL + off);
    }
  f32x4 accI[2][4], accA[2][4];
#pragma unroll
  for (int mt = 0; mt < 2; ++mt)
#pragma unroll
    for (int nt = 0; nt < 4; ++nt) {
      accI[mt][nt] = f32x4{0.f, 0.f, 0.f, 0.f};
      accA[mt][nt] = f32x4{0.f, 0.f, 0.f, 0.f};
    }
  __syncthreads();
#pragma unroll
  for (int mt = 0; mt < 2; ++mt) {
    int mrow = wv * 32 + mt * 16 + fm;
#pragma unroll
    for (int ks = 0; ks < 2; ++ks) {
      bf16x8 ah = *(const bf16x8*)&xcH[mrow * XP + ks * 32 + fq * 8];
      bf16x8 al = *(const bf16x8*)&xcL[mrow * XP + ks * 32 + fq * 8];
#pragma unroll
      for (int nt = 0; nt < 4; ++nt) {
        accI[mt][nt] = __builtin_amdgcn_mfma_f32_16x16x32_bf16(ah, bIh[nt][ks], accI[mt][nt], 0, 0, 0);
        accI[mt][nt] = __builtin_amdgcn_mfma_f32_16x16x32_bf16(ah, bIl[nt][ks], accI[mt][nt], 0, 0, 0);
        accI[mt][nt] = __builtin_amdgcn_mfma_f32_16x16x32_bf16(al, bIh[nt][ks], accI[mt][nt], 0, 0, 0);
        accA[mt][nt] = __builtin_amdgcn_mfma_f32_16x16x32_bf16(ah, bAh[nt][ks], accA[mt][nt], 0, 0, 0);
        accA[mt][nt] = __builtin_amdgcn_mfma_f32_16x16x32_bf16(ah, bAl[nt][ks], accA[mt][nt], 0, 0, 0);
        accA[mt][nt] = __builtin_amdgcn_mfma_f32_16x16x32_bf16(al, bAh[nt][ks], accA[mt][nt], 0, 0, 0);
      }
    }
  }
  // epilogue: all-native-transcendental
#pragma unroll
  for (int nt = 0; nt < 4; ++nt) {
    int colg = (h << 6) + nt * 16 + fm;
    float biv = bi[colg], bav = ba[colg];
    float sp8 = -8.0f * spbuf[colg];
#pragma unroll
    for (int mt = 0; mt < 2; ++mt) {
#pragma unroll
      for (int r = 0; r < 4; ++r) {
        int mrow = wv * 32 + mt * 16 + fq * 4 + r;
        int t = t0 + mrow;
        float xcv = bf2f(xcH[mrow * XP + nt * 16 + fm]) + bf2f(xcL[mrow * XP + nt * 16 + fm]);
        float gx = frcp(1.0f + fexp(-(accI[mt][nt][r] + biv)));
        float ga = frcp(1.0f + fexp(-(accA[mt][nt][r] + bav)));
        float la = sp8 * ga;
        float av = fexp(la);
        float mult = __builtin_amdgcn_sqrtf(fmaxf(1.0f - fexp(2.0f * la), 0.0f));
        if (reset[b * 2048 + t]) { mult = 1.0f; av = 0.0f; }
        size_t idx = ((size_t)(b * 2048 + t)) * 512 + colg;
        aq_out[idx] = (unsigned short)fminf(av * 65536.0f + 0.5f, 65535.0f);
        nrm[idx] = f2bf(xcv * gx * mult);
      }
    }
  }
}

// ---------------- chunked linear scan (a as u16 fixed-point, 4 ch/thread)
__global__ void scan1_kernel(const unsigned short* __restrict__ aq, const unsigned short* __restrict__ nrm,
                             float* __restrict__ cA, float* __restrict__ cH) {
  int g = blockIdx.x * 256 + threadIdx.x;  // 131072
  int c4 = (g & 127) << 2, k = (g >> 7) & 31, b = g >> 12;
  size_t base = ((size_t)(b * 2048 + k * 64)) * 512 + c4;
  float A[4] = {1.f, 1.f, 1.f, 1.f}, h[4] = {0.f, 0.f, 0.f, 0.f};
#pragma unroll 4
  for (int i = 0; i < 64; ++i) {
    u16x4 av = *(const u16x4*)(aq + base + (size_t)i * 512);
    u16x4 nv = *(const u16x4*)(nrm + base + (size_t)i * 512);
#pragma unroll
    for (int j = 0; j < 4; ++j) {
      float a = (float)av[j] * (1.0f / 65536.0f);
      A[j] *= a;
      h[j] = fmaf(a, h[j], bf2f(nv[j]));
    }
  }
  int ci = ((b * 32 + k) << 9) + c4;
#pragma unroll
  for (int j = 0; j < 4; ++j) { cA[ci + j] = A[j]; cH[ci + j] = h[j]; }
}

__global__ void scan2_kernel(const float* __restrict__ cA, const float* __restrict__ cH,
                             const float* __restrict__ h0, float* __restrict__ hinit) {
  int b = blockIdx.x, c = threadIdx.x;
  float h = h0[b * 512 + c];
  for (int k = 0; k < 32; ++k) {
    int ci = ((b * 32 + k) << 9) + c;
    hinit[ci] = h;
    h = fmaf(cA[ci], h, cH[ci]);
  }
}

__global__ void scan3_kernel(const unsigned short* __restrict__ aq, const unsigned short* __restrict__ nrm,
                             const float* __restrict__ hinit, const unsigned short* __restrict__ ybuf,
                             unsigned short* __restrict__ p) {
  int g = blockIdx.x * 256 + threadIdx.x;  // 131072
  int c4 = (g & 127) << 2, k = (g >> 7) & 31, b = g >> 12;
  size_t base = ((size_t)(b * 2048 + k * 64)) * 512 + c4;
  int ci = ((b * 32 + k) << 9) + c4;
  float h[4];
#pragma unroll
  for (int j = 0; j < 4; ++j) h[j] = hinit[ci + j];
#pragma unroll 4
  for (int i = 0; i < 64; ++i) {
    u16x4 av = *(const u16x4*)(aq + base + (size_t)i * 512);
    u16x4 nv = *(const u16x4*)(nrm + base + (size_t)i * 512);
    u16x4 yv = *(const u16x4*)(ybuf + base + (size_t)i * 512);
    u16x4 pv;
#pragma unroll
    for (int j = 0; j < 4; ++j) {
      float a = (float)av[j] * (1.0f / 65536.0f);
      h[j] = fmaf(a, h[j], bf2f(nv[j]));
      pv[j] = f2bf(h[j] * bf2f(yv[j]));
    }
    *(u16x4*)(p + base + (size_t)i * 512) = pv;
  }
}

// ---------------- GEMM2: out = p @ w_out + b_out (fp32 out)
// XCD-chunked swizzle + 2 k-steps per barrier round (double-buffered halves).
__global__ __launch_bounds__(256, 2)
void gemm_out_kernel(const unsigned short* __restrict__ p,
                     const unsigned short* __restrict__ woT,
                     const float* __restrict__ bout, float* __restrict__ out) {
  __shared__ __align__(16) unsigned short As[2 * 128 * 32];
  __shared__ __align__(16) unsigned short Bs[2 * 128 * 32];
  const int tid = threadIdx.x, lane = tid & 63, wv = tid >> 6;
  const int lg = ((blockIdx.x & 7) << 8) | (blockIdx.x >> 3);   // XCD-chunked
  const int m0 = (lg >> 2) << 7, n0 = (lg & 3) << 7;
  const int sr = lane >> 2, sk = (lane & 3) * 8;
  const int wm = (wv >> 1) << 6, wn = (wv & 1) << 6;
  const int fm = lane & 15, fq = lane >> 4;

  f32x4 acc[4][4];
#pragma unroll
  for (int i = 0; i < 4; ++i)
#pragma unroll
    for (int j = 0; j < 4; ++j) acc[i][j] = f32x4{0.f, 0.f, 0.f, 0.f};

  const unsigned short* ga = p   + (size_t)(m0 + wv * 32 + sr) * 512 + sk;
  const unsigned short* gb = woT + (size_t)(n0 + wv * 32 + sr) * 512 + sk;
  unsigned short* lA = As + wv * 1024;
  unsigned short* lB = Bs + wv * 1024;

  for (int r = 0; r < 8; ++r) {
    const int k0 = r << 6;
    __syncthreads();
#pragma unroll
    for (int bb = 0; bb < 2; ++bb) {
      gl2lds16(ga + k0 + bb * 32,            lA + bb * 4096);
      gl2lds16(ga + k0 + bb * 32 + 16 * 512, lA + bb * 4096 + 512);
      gl2lds16(gb + k0 + bb * 32,            lB + bb * 4096);
      gl2lds16(gb + k0 + bb * 32 + 16 * 512, lB + bb * 4096 + 512);
    }
    __syncthreads();
#pragma unroll
    for (int bb = 0; bb < 2; ++bb) {
      const unsigned short* Ab = As + bb * 4096;
      const unsigned short* Bb = Bs + bb * 4096;
      bf16x8 af[4], bfr[4];
#pragma unroll
      for (int i = 0; i < 4; ++i)
        af[i] = *(const bf16x8*)&Ab[(wm + i * 16 + fm) * 32 + fq * 8];
#pragma unroll
      for (int j = 0; j < 4; ++j)
        bfr[j] = *(const bf16x8*)&Bb[(wn + j * 16 + fm) * 32 + fq * 8];
#pragma unroll
      for (int i = 0; i < 4; ++i)
#pragma unroll
        for (int j = 0; j < 4; ++j)
          acc[i][j] = __builtin_amdgcn_mfma_f32_16x16x32_bf16(af[i], bfr[j], acc[i][j], 0, 0, 0);
    }
  }
#pragma unroll
  for (int i = 0; i < 4; ++i) {
#pragma unroll
    for (int j = 0; j < 4; ++j) {
      int col = n0 + wn + j * 16 + fm;
      float bv = bout[col];
#pragma unroll
      for (int r = 0; r < 4; ++r) {
        int row = m0 + wm + i * 16 + fq * 4 + r;
        out[(size_t)row * 512 + col] = acc[i][j][r] + bv;
      }
    }
  }
}

extern "C" void kernel_launch(void* const* d_in, const int* in_sizes, int n_in,
                              void* d_out, int out_size, void* d_ws, size_t ws_size,
                              hipStream_t stream) {
  const float* x             = (const float*)d_in[0];
  const unsigned char* reset = (const unsigned char*)d_in[1];
  const float* h0            = (const float*)d_in[2];
  const float* b_x           = (const float*)d_in[4];
  const float* b_y           = (const float*)d_in[6];
  const float* conv_w        = (const float*)d_in[7];
  const float* conv_b        = (const float*)d_in[8];
  const float* bi            = (const float*)d_in[11];
  const float* ba            = (const float*)d_in[13];
  const float* b_out         = (const float*)d_in[15];

  char* ws = (char*)d_ws;
  unsigned short* xbp  = (unsigned short*)(ws);               // 64MB bf16; reused as p
  unsigned short* ybuf = (unsigned short*)(ws + 64 * MBY);    // 64MB bf16
  unsigned short* aq   = (unsigned short*)(ws + 128 * MBY);   // 64MB u16 fixed-point a
  unsigned short* nrm  = (unsigned short*)(ws + 192 * MBY);   // 64MB bf16
  float* cA            = (float*)(ws + 256 * MBY);
  float* cH            = (float*)(ws + 258 * MBY);
  float* hinit         = (float*)(ws + 260 * MBY);
  unsigned short* wxT  = (unsigned short*)(ws + 262 * MBY);
  unsigned short* wyT  = (unsigned short*)(ws + 262 * MBY + 524288);
  unsigned short* woT  = (unsigned short*)(ws + 263 * MBY);
  unsigned short* wiTH = (unsigned short*)(ws + 263 * MBY + 524288);
  unsigned short* wiTL = wiTH + 32768;
  unsigned short* waTH = wiTL + 32768;
  unsigned short* waTL = waTH + 32768;
  float* spbuf         = (float*)(waTL + 32768);
  unsigned short* p    = xbp;

  hipLaunchKernelGGL(prep_misc_kernel, dim3(3202), dim3(256), 0, stream,
                     (const float*)d_in[3], (const float*)d_in[5], (const float*)d_in[14],
                     (const float*)d_in[10], (const float*)d_in[12], (const float*)d_in[9],
                     wxT, wyT, woT, wiTH, wiTL, waTH, waTL, spbuf);
  hipLaunchKernelGGL(gemm_dual_kernel, dim3(2048), dim3(256), 0, stream,
                     x, wxT, wyT, b_x, b_y, xbp, ybuf);
  hipLaunchKernelGGL(conv_gates_kernel, dim3(16, 8, 32), dim3(256), 0, stream,
                     xbp, reset, conv_w, conv_b, spbuf, wiTH, wiTL, waTH, waTL,
                     bi, ba, aq, nrm);
  hipLaunchKernelGGL(scan1_kernel, dim3(512), dim3(256), 0, stream, aq, nrm, cA, cH);
  hipLaunchKernelGGL(scan2_kernel, dim3(32), dim3(512), 0, stream, cA, cH, h0, hinit);
  hipLaunchKernelGGL(scan3_kernel, dim3(512), dim3(256), 0, stream, aq, nrm, hinit, ybuf, p);
  hipLaunchKernelGGL(gemm_out_kernel, dim3(2048), dim3(256), 0, stream, p, woT, b_out, (float*)d_out);
}